// Round 1
// baseline (112.262 us; speedup 1.0000x reference)
//
#include <hip/hip_runtime.h>

#define BATCH 512
#define SEQL  512
#define EMBD  100
#define NCH   14
#define NCLS  5

__global__ __launch_bounds__(256, 2) void cnn_fused(
    const int* __restrict__ words,
    const float* __restrict__ emb,
    const float* __restrict__ w2, const float* __restrict__ b2,
    const float* __restrict__ w3, const float* __restrict__ b3,
    const float* __restrict__ w4, const float* __restrict__ b4,
    const float* __restrict__ w5, const float* __restrict__ b5,
    const float* __restrict__ fcw, const float* __restrict__ fcb,
    float* __restrict__ out)
{
    // channel -> kernel size, and offset of its [j][d] weight slab in wl
    constexpr int KC[NCH]   = {2,2, 3,3,3, 4,4,4,4, 5,5,5,5,5};
    constexpr int WOFF[NCH] = {0,200, 400,700,1000, 1300,1700,2100,2500,
                               2900,3400,3900,4400,4900};   // sum k*100 = 5400

    __shared__ float wl[5400];      // [c][j][d] layout, d contiguous (16B-aligned slabs)
    __shared__ float bias_s[NCH];
    __shared__ float red[4][NCH];

    const int b   = blockIdx.x;
    const int tid = threadIdx.x;

    // ---- stage + repack weights: input layout [o][d][j] -> wl[c][j*100 + d] ----
    auto stage = [&](const float* __restrict__ w, int O, int K, int cbase) {
        const int n = O * EMBD * K;
        for (int i = tid; i < n; i += 256) {
            int o   = i / (EMBD * K);
            int rem = i - o * (EMBD * K);
            int d   = rem / K;
            int j   = rem - d * K;
            wl[WOFF[cbase + o] + j * EMBD + d] = w[i];
        }
    };
    stage(w2, 2, 2, 0);
    stage(w3, 3, 3, 2);
    stage(w4, 4, 4, 5);
    stage(w5, 5, 5, 9);
    if (tid < NCH) {
        const float* bp = (tid < 2) ? &b2[tid] : (tid < 5) ? &b3[tid - 2]
                        : (tid < 9) ? &b4[tid - 5] : &b5[tid - 9];
        bias_s[tid] = *bp;
    }
    __syncthreads();

    // ---- each thread: 2 consecutive positions t0, t0+1 ----
    const int t0 = tid * 2;
    int tok[6];
    #pragma unroll
    for (int r = 0; r < 6; ++r) {
        int u = t0 + r;
        tok[r] = (u < SEQL) ? words[b * SEQL + u] : 0;   // clamped rows feed only masked outputs
    }
    const float4* __restrict__ emb4 = reinterpret_cast<const float4*>(emb);

    float y[2][NCH];
    #pragma unroll
    for (int p = 0; p < 2; ++p)
        #pragma unroll
        for (int c = 0; c < NCH; ++c) y[p][c] = 0.f;

    #pragma unroll 1
    for (int q = 0; q < 25; ++q) {           // d-chunk of 4 floats
        float4 xr[6];
        #pragma unroll
        for (int r = 0; r < 6; ++r) xr[r] = emb4[tok[r] * 25 + q];
        #pragma unroll
        for (int j = 0; j < 5; ++j) {
            #pragma unroll
            for (int c = 0; c < NCH; ++c) {
                if (KC[c] > j) {             // compile-time folded
                    const float4 wv = *reinterpret_cast<const float4*>(
                        &wl[WOFF[c] + j * EMBD + q * 4]);   // uniform addr -> LDS broadcast
                    #pragma unroll
                    for (int p = 0; p < 2; ++p) {
                        y[p][c] += xr[p + j].x * wv.x;
                        y[p][c] += xr[p + j].y * wv.y;
                        y[p][c] += xr[p + j].z * wv.z;
                        y[p][c] += xr[p + j].w * wv.w;
                    }
                }
            }
        }
    }

    // ---- bias + relu + max over valid positions ----
    float m[NCH];
    #pragma unroll
    for (int c = 0; c < NCH; ++c) {
        float v = 0.f;                        // relu floor doubles as -inf substitute
        #pragma unroll
        for (int p = 0; p < 2; ++p) {
            int t = t0 + p;
            if (t + KC[c] <= SEQL)            // VALID conv range: t <= L - k
                v = fmaxf(v, y[p][c] + bias_s[c]);
        }
        m[c] = v;
    }

    // ---- 64-lane max reduce, then cross-wave via LDS ----
    #pragma unroll
    for (int c = 0; c < NCH; ++c) {
        float v = m[c];
        #pragma unroll
        for (int off = 32; off > 0; off >>= 1)
            v = fmaxf(v, __shfl_xor(v, off, 64));
        m[c] = v;
    }
    const int wave = tid >> 6;
    const int lane = tid & 63;
    if (lane == 0) {
        #pragma unroll
        for (int c = 0; c < NCH; ++c) red[wave][c] = m[c];
    }
    __syncthreads();

    // ---- FC: out[b][cls] = fcb + sum_o fcw[cls][o] * feat[o] ----
    if (tid < NCLS) {
        float acc = fcb[tid];
        #pragma unroll
        for (int o = 0; o < NCH; ++o) {
            float f = fmaxf(fmaxf(red[0][o], red[1][o]),
                            fmaxf(red[2][o], red[3][o]));
            acc += fcw[tid * NCH + o] * f;
        }
        out[b * NCLS + tid] = acc;
    }
}

extern "C" void kernel_launch(void* const* d_in, const int* in_sizes, int n_in,
                              void* d_out, int out_size, void* d_ws, size_t ws_size,
                              hipStream_t stream) {
    const int*   words = (const int*)  d_in[0];
    const float* emb   = (const float*)d_in[1];
    const float* w2    = (const float*)d_in[2];
    const float* b2    = (const float*)d_in[3];
    const float* w3    = (const float*)d_in[4];
    const float* b3    = (const float*)d_in[5];
    const float* w4    = (const float*)d_in[6];
    const float* b4    = (const float*)d_in[7];
    const float* w5    = (const float*)d_in[8];
    const float* b5    = (const float*)d_in[9];
    const float* fcw   = (const float*)d_in[10];
    const float* fcb   = (const float*)d_in[11];
    float* out = (float*)d_out;

    hipLaunchKernelGGL(cnn_fused, dim3(BATCH), dim3(256), 0, stream,
                       words, emb, w2, b2, w3, b3, w4, b4, w5, b5, fcw, fcb, out);
}

// Round 2
// 104.403 us; speedup vs baseline: 1.0753x; 1.0753x over previous
//
#include <hip/hip_runtime.h>

#define BATCH 512
#define SEQL  512
#define EMBD  100
#define NCH   14
#define NCLS  5

__global__ __launch_bounds__(256, 2) void cnn_fused(
    const int* __restrict__ words,
    const float* __restrict__ emb,
    const float* __restrict__ w2, const float* __restrict__ b2,
    const float* __restrict__ w3, const float* __restrict__ b3,
    const float* __restrict__ w4, const float* __restrict__ b4,
    const float* __restrict__ w5, const float* __restrict__ b5,
    const float* __restrict__ fcw, const float* __restrict__ fcb,
    float* __restrict__ out)
{
    // channel -> kernel size, and offset of its [j][d] weight slab in wl
    constexpr int KC[NCH]   = {2,2, 3,3,3, 4,4,4,4, 5,5,5,5,5};
    constexpr int WOFF[NCH] = {0,200, 400,700,1000, 1300,1700,2100,2500,
                               2900,3400,3900,4400,4900};   // sum k*100 = 5400

    __shared__ float wl[5400];      // [c][j][d] layout, d contiguous (16B-aligned slabs)
    __shared__ float bias_s[NCH];
    __shared__ float red[4][NCH];

    const int b   = blockIdx.x;
    const int tid = threadIdx.x;

    // ---- stage + repack weights: input layout [o][d][j] -> wl[c][j*100 + d] ----
    auto stage = [&](const float* __restrict__ w, int O, int K, int cbase) {
        const int n = O * EMBD * K;
        for (int i = tid; i < n; i += 256) {
            int o   = i / (EMBD * K);
            int rem = i - o * (EMBD * K);
            int d   = rem / K;
            int j   = rem - d * K;
            wl[WOFF[cbase + o] + j * EMBD + d] = w[i];
        }
    };
    stage(w2, 2, 2, 0);
    stage(w3, 3, 3, 2);
    stage(w4, 4, 4, 5);
    stage(w5, 5, 5, 9);
    if (tid < NCH) {
        const float* bp = (tid < 2) ? &b2[tid] : (tid < 5) ? &b3[tid - 2]
                        : (tid < 9) ? &b4[tid - 5] : &b5[tid - 9];
        bias_s[tid] = *bp;
    }
    __syncthreads();

    // ---- each thread: 2 consecutive positions t0, t0+1 ----
    const int t0 = tid * 2;
    int tok[6];
    #pragma unroll
    for (int r = 0; r < 6; ++r) {
        int u = t0 + r;
        tok[r] = (u < SEQL) ? words[b * SEQL + u] : 0;   // clamped rows feed only masked outputs
    }
    const float4* __restrict__ emb4 = reinterpret_cast<const float4*>(emb);
    const float4* rowp[6];
    #pragma unroll
    for (int r = 0; r < 6; ++r) rowp[r] = emb4 + (long)tok[r] * 25;

    float y[2][NCH];
    #pragma unroll
    for (int p = 0; p < 2; ++p)
        #pragma unroll
        for (int c = 0; c < NCH; ++c) y[p][c] = 0.f;

    // one FMA block over a 4-float d-chunk held in xr, weights at d-chunk q
    auto compute = [&](const float4 (&xr)[6], int q) {
        const float* wq = &wl[q * 4];
        #pragma unroll
        for (int j = 0; j < 5; ++j) {
            #pragma unroll
            for (int c = 0; c < NCH; ++c) {
                if (KC[c] > j) {             // compile-time folded
                    const float4 wv = *reinterpret_cast<const float4*>(
                        wq + WOFF[c] + j * EMBD);   // uniform addr -> LDS broadcast
                    #pragma unroll
                    for (int p = 0; p < 2; ++p) {
                        y[p][c] += xr[p + j].x * wv.x;
                        y[p][c] += xr[p + j].y * wv.y;
                        y[p][c] += xr[p + j].z * wv.z;
                        y[p][c] += xr[p + j].w * wv.w;
                    }
                }
            }
        }
    };

    // ---- software-pipelined q-loop: prefetch q+1/q+2 while computing q ----
    float4 xA[6], xB[6];
    #pragma unroll
    for (int r = 0; r < 6; ++r) xA[r] = rowp[r][0];

    #pragma unroll 1
    for (int q = 0; q < 24; q += 2) {
        #pragma unroll
        for (int r = 0; r < 6; ++r) xB[r] = rowp[r][q + 1];   // prefetch odd chunk
        compute(xA, q);
        #pragma unroll
        for (int r = 0; r < 6; ++r) xA[r] = rowp[r][q + 2];   // prefetch next even chunk
        compute(xB, q + 1);
    }
    compute(xA, 24);   // preloaded in the q=22 iteration

    // ---- bias + relu + max over valid positions ----
    float m[NCH];
    #pragma unroll
    for (int c = 0; c < NCH; ++c) {
        float v = 0.f;                        // relu floor doubles as -inf substitute
        #pragma unroll
        for (int p = 0; p < 2; ++p) {
            int t = t0 + p;
            if (t + KC[c] <= SEQL)            // VALID conv range: t <= L - k
                v = fmaxf(v, y[p][c] + bias_s[c]);
        }
        m[c] = v;
    }

    // ---- 64-lane max reduce, then cross-wave via LDS ----
    #pragma unroll
    for (int c = 0; c < NCH; ++c) {
        float v = m[c];
        #pragma unroll
        for (int off = 32; off > 0; off >>= 1)
            v = fmaxf(v, __shfl_xor(v, off, 64));
        m[c] = v;
    }
    const int wave = tid >> 6;
    const int lane = tid & 63;
    if (lane == 0) {
        #pragma unroll
        for (int c = 0; c < NCH; ++c) red[wave][c] = m[c];
    }
    __syncthreads();

    // ---- FC: out[b][cls] = fcb + sum_o fcw[cls][o] * feat[o] ----
    if (tid < NCLS) {
        float acc = fcb[tid];
        #pragma unroll
        for (int o = 0; o < NCH; ++o) {
            float f = fmaxf(fmaxf(red[0][o], red[1][o]),
                            fmaxf(red[2][o], red[3][o]));
            acc += fcw[tid * NCH + o] * f;
        }
        out[b * NCLS + tid] = acc;
    }
}

extern "C" void kernel_launch(void* const* d_in, const int* in_sizes, int n_in,
                              void* d_out, int out_size, void* d_ws, size_t ws_size,
                              hipStream_t stream) {
    const int*   words = (const int*)  d_in[0];
    const float* emb   = (const float*)d_in[1];
    const float* w2    = (const float*)d_in[2];
    const float* b2    = (const float*)d_in[3];
    const float* w3    = (const float*)d_in[4];
    const float* b3    = (const float*)d_in[5];
    const float* w4    = (const float*)d_in[6];
    const float* b4    = (const float*)d_in[7];
    const float* w5    = (const float*)d_in[8];
    const float* b5    = (const float*)d_in[9];
    const float* fcw   = (const float*)d_in[10];
    const float* fcb   = (const float*)d_in[11];
    float* out = (float*)d_out;

    hipLaunchKernelGGL(cnn_fused, dim3(BATCH), dim3(256), 0, stream,
                       words, emb, w2, b2, w3, b3, w4, b4, w5, b5, fcw, fcb, out);
}